// Round 15
// baseline (2010.304 us; speedup 1.0000x reference)
//
#include <hip/hip_runtime.h>
#include <math.h>

#define NB 16
#define NM 2048
#define NCTR 512
#define NK 32
#define NDIM 384

typedef unsigned long long ull;
typedef unsigned int uint;
typedef unsigned short ushort;
typedef __attribute__((ext_vector_type(8))) short bf16x8;
typedef __attribute__((ext_vector_type(4))) float f32x4;

// Exact (no-FMA-contraction) squared distance, matching XLA's per-op fp32.
__device__ __forceinline__ float dist2_exact(float ax, float ay, float az,
                                             float bx, float by, float bz) {
  float dx = __fsub_rn(ax, bx);
  float dy = __fsub_rn(ay, by);
  float dz = __fsub_rn(az, bz);
  return __fadd_rn(__fadd_rn(__fmul_rn(dx, dx), __fmul_rn(dy, dy)),
                   __fmul_rn(dz, dz));
}

__device__ __forceinline__ float gelu_f(float x) {
  return 0.5f * x * (1.0f + erff(x * 0.70710678118654752f));
}

// fp32 -> bf16 round-to-nearest-even (bit trick), and back.
__device__ __forceinline__ ushort f2bf(float f) {
  uint u = __float_as_uint(f);
  return (ushort)((u + 0x7FFFu + ((u >> 16) & 1u)) >> 16);
}
__device__ __forceinline__ float bf2f(ushort h) {
  return __uint_as_float(((uint)h) << 16);
}

// Split 8 fp32 into bf16 hi / lo packed words (2 bf16 per uint).
__device__ __forceinline__ void cvt8(float4 p, float4 q, uint4& hi, uint4& lo) {
  float v0 = p.x, v1 = p.y, v2 = p.z, v3 = p.w;
  float v4 = q.x, v5 = q.y, v6 = q.z, v7 = q.w;
  ushort h0 = f2bf(v0), h1 = f2bf(v1), h2 = f2bf(v2), h3 = f2bf(v3);
  ushort h4 = f2bf(v4), h5 = f2bf(v5), h6 = f2bf(v6), h7 = f2bf(v7);
  ushort l0 = f2bf(v0 - bf2f(h0)), l1 = f2bf(v1 - bf2f(h1));
  ushort l2 = f2bf(v2 - bf2f(h2)), l3 = f2bf(v3 - bf2f(h3));
  ushort l4 = f2bf(v4 - bf2f(h4)), l5 = f2bf(v5 - bf2f(h5));
  ushort l6 = f2bf(v6 - bf2f(h6)), l7 = f2bf(v7 - bf2f(h7));
  hi.x = (uint)h0 | ((uint)h1 << 16); hi.y = (uint)h2 | ((uint)h3 << 16);
  hi.z = (uint)h4 | ((uint)h5 << 16); hi.w = (uint)h6 | ((uint)h7 << 16);
  lo.x = (uint)l0 | ((uint)l1 << 16); lo.y = (uint)l2 | ((uint)l3 << 16);
  lo.z = (uint)l4 | ((uint)l5 << 16); lo.w = (uint)l6 | ((uint)l7 << 16);
}

__device__ __forceinline__ void split_store(float v, ushort* H, ushort* L,
                                            size_t off) {
  ushort hi = f2bf(v);
  H[off] = hi;
  L[off] = f2bf(v - bf2f(hi));
}

// ---------------------------------------------------------------------------
// Combined weight pre-split descriptor.
// ---------------------------------------------------------------------------
struct WAll {
  const float* src[8];
  ushort* dst[8];
  int K8[8];
  int N[8];
  int Ksrc[8];
  int blk0[9];
};

// ---------------------------------------------------------------------------
// Merged FPS + weight-split (round-10 best: 256 threads, 4-wave FPS,
// 8 pts/lane — spill-free at VGPR_Count 52).
// ---------------------------------------------------------------------------
__global__ __launch_bounds__(256)
void fps_wconv(const float* __restrict__ pc, float* __restrict__ centers,
               WAll a) {
  __shared__ float4 pos4[NM];
  __shared__ ull red[2][4];
  if (blockIdx.x >= 16) {
    int bid = blockIdx.x - 16;
    int f = 0;
#pragma unroll
    for (int i = 1; i < 8; ++i) f += (bid >= a.blk0[i]);
    int K8 = a.K8[f], N = a.N[f], Ksrc = a.Ksrc[f];
    int c = (bid - a.blk0[f]) * 256 + threadIdx.x;
    if (c >= K8 * N) return;
    const float* W = a.src[f];
    ushort* out = a.dst[f];
    int kb = c / N, n = c - kb * N;
    float v[8];
#pragma unroll
    for (int i = 0; i < 8; ++i) {
      int row = kb * 8 + i;
      v[i] = (row < Ksrc) ? W[(size_t)row * N + n] : 0.f;
    }
    float4 p, q;
    p.x = v[0]; p.y = v[1]; p.z = v[2]; p.w = v[3];
    q.x = v[4]; q.y = v[5]; q.z = v[6]; q.w = v[7];
    uint4 hi, lo;
    cvt8(p, q, hi, lo);
    *(uint4*)(out + (size_t)c * 8) = hi;
    *(uint4*)(out + (size_t)(K8 * N + c) * 8) = lo;
    return;
  }
  int b = blockIdx.x;
  const float* pb = pc + (size_t)b * (NM * 3);
  int tid = threadIdx.x, lane = tid & 63, wv = tid >> 6;
  float px[8], py[8], pz[8];
#pragma unroll
  for (int i = 0; i < 8; ++i) {
    int p = tid + 256 * i;
    float x = pb[3 * p], y = pb[3 * p + 1], z = pb[3 * p + 2];
    px[i] = x; py[i] = y; pz[i] = z;
    pos4[p] = make_float4(x, y, z, 0.f);
  }
  __syncthreads();
  float* cb = centers + (size_t)b * (NCTR * 3);
  float4 s0 = pos4[0];
  float sx = s0.x, sy = s0.y, sz = s0.z;
  if (tid == 0) { cb[0] = sx; cb[1] = sy; cb[2] = sz; }
  float d[8];
  for (int n = 1; n < NCTR; ++n) {
    ull best = 0;
#pragma unroll
    for (int i = 0; i < 8; ++i) {
      int p = tid + 256 * i;
      float nd = dist2_exact(px[i], py[i], pz[i], sx, sy, sz);
      d[i] = (n == 1) ? nd : fminf(d[i], nd);
      ull key = ((ull)__float_as_uint(d[i]) << 32) | (unsigned)(0x7FFFFFFF - p);
      best = best > key ? best : key;
    }
    float dl = __uint_as_float((uint)(best >> 32));
    float wm = dl;
#pragma unroll
    for (int off = 32; off; off >>= 1) wm = fmaxf(wm, __shfl_xor(wm, off));
    ull mask = __ballot(dl == wm);
    ull wkey;
    if (mask & (mask - 1)) {
      wkey = best;
#pragma unroll
      for (int off = 32; off; off >>= 1) {
        ull o = __shfl_xor(wkey, off);
        wkey = wkey > o ? wkey : o;
      }
    } else {
      int src = __ffsll((long long)mask) - 1;
      wkey = __shfl(best, src);
    }
    if (lane == 0) red[n & 1][wv] = wkey;
    __syncthreads();
    ull g0 = red[n & 1][0], g1 = red[n & 1][1];
    ull g2 = red[n & 1][2], g3 = red[n & 1][3];
    ull ga = g0 > g1 ? g0 : g1;
    ull gc2 = g2 > g3 ? g2 : g3;
    ull gb = ga > gc2 ? ga : gc2;
    int j = 0x7FFFFFFF - (int)(unsigned)(gb & 0xFFFFFFFFull);
    float4 np = pos4[j];
    sx = np.x; sy = np.y; sz = np.z;
    if (tid == 0) { cb[n * 3] = sx; cb[n * 3 + 1] = sy; cb[n * 3 + 2] = sz; }
  }
}

// ---------------------------------------------------------------------------
// KNN v2 (unchanged — spill-free).
// ---------------------------------------------------------------------------
__global__ __launch_bounds__(256, 2)
void knn_kernel(const float* __restrict__ pc, const float* __restrict__ centers,
                int* __restrict__ nn) {
  __shared__ float pos[NM * 3];
  int b = blockIdx.x >> 7;
  int n0 = (blockIdx.x & 127) << 2;
  const float* pb = pc + (size_t)b * (NM * 3);
  for (int i = threadIdx.x; i < NM * 3; i += 256) pos[i] = pb[i];
  __syncthreads();
  int wv = threadIdx.x >> 6, lane = threadIdx.x & 63;
  int gc = b * NCTR + n0 + wv;
  float cx = centers[gc * 3], cy = centers[gc * 3 + 1], cz = centers[gc * 3 + 2];
  ull key[32];
  ull gmin[4];
#pragma unroll
  for (int g = 0; g < 4; ++g) {
    gmin[g] = ~0ull;
#pragma unroll
    for (int i = 0; i < 8; ++i) {
      int r = g * 8 + i;
      int p = lane + (r << 6);
      float nd = dist2_exact(pos[3 * p], pos[3 * p + 1], pos[3 * p + 2], cx, cy, cz);
      key[r] = ((ull)__float_as_uint(nd) << 11) | (unsigned)p;
      gmin[g] = gmin[g] < key[r] ? gmin[g] : key[r];
    }
  }
  ull a01 = gmin[0] < gmin[1] ? gmin[0] : gmin[1];
  ull a23 = gmin[2] < gmin[3] ? gmin[2] : gmin[3];
  ull lmin = a01 < a23 ? a01 : a23;
  int* nnc = nn + (size_t)gc * NK;
  for (int round = 0; round < NK; ++round) {
    ull w = lmin;
#pragma unroll
    for (int off = 32; off; off >>= 1) {
      ull o = __shfl_xor(w, off);
      w = w < o ? w : o;
    }
    if (lmin == w) {
      nnc[round] = (int)(w & 2047ull);
#pragma unroll
      for (int g = 0; g < 4; ++g) {
        if (gmin[g] == w) {
          gmin[g] = ~0ull;
#pragma unroll
          for (int i = 0; i < 8; ++i) {
            int r = g * 8 + i;
            key[r] = (key[r] == w) ? ~0ull : key[r];
            gmin[g] = gmin[g] < key[r] ? gmin[g] : key[r];
          }
        }
      }
      ull b01 = gmin[0] < gmin[1] ? gmin[0] : gmin[1];
      ull b23 = gmin[2] < gmin[3] ? gmin[2] : gmin[3];
      lmin = b01 < b23 ? b01 : b23;
    }
  }
}

// ---------------------------------------------------------------------------
// Fused edge pipeline (unchanged).
// ---------------------------------------------------------------------------
__global__ __launch_bounds__(256, 2)
void edge_mfma(const float* __restrict__ pc, const float* __restrict__ centers,
               const int* __restrict__ nn, const ushort* __restrict__ lw1s,
               const float* __restrict__ lb1, const ushort* __restrict__ lw2s,
               const float* __restrict__ lb2, ushort* __restrict__ hH,
               ushort* __restrict__ hL) {
  __shared__ __align__(16) ushort featH[4096], featL[4096];
  __shared__ __align__(16) ushort t1H[16384], t1L[16384];
  int tid = threadIdx.x;
  int w = tid >> 6, lane = tid & 63;
  int l15 = lane & 15, l4 = lane >> 4;
  int wbase = w << 6;
  {
    int e = tid >> 2, s = tid & 3;
    int ge = blockIdx.x * 64 + e;
    int c = ge >> 5;
    int b = c >> 9;
    int j = nn[ge];
    const float* sp = pc + ((size_t)b * NM + j) * 3;
    float rx = sp[0] - centers[c * 3];
    float ry = sp[1] - centers[c * 3 + 1];
    float rz = sp[2] - centers[c * 3 + 2];
    auto putk = [&](int k, float v) {
      ushort hi = f2bf(v);
      ushort lo = f2bf(v - bf2f(hi));
      int idx = ((k >> 3) * 64 + e) * 8 + (k & 7);
      featH[idx] = hi;
      featL[idx] = lo;
    };
    if (s < 3) {
      float r = (s == 0) ? rx : (s == 1) ? ry : rz;
#pragma unroll
      for (int f = 0; f < 8; ++f) {
        float ef = (float)(M_PI * (double)(1 << f));
        float p = r * ef;
        putk(3 + 8 * s + f, sinf(p));
        putk(27 + 8 * s + f, cosf(p));
      }
    } else {
      putk(0, rx);
      putk(1, ry);
      putk(2, rz);
#pragma unroll
      for (int k = 51; k < 64; ++k) putk(k, 0.f);
    }
  }
  __syncthreads();
  const ushort* lw1H = lw1s;
  const ushort* lw1L = lw1s + 8 * 256 * 8;
  f32x4 acc1[4][4];
#pragma unroll
  for (int i = 0; i < 4; ++i)
#pragma unroll
    for (int j = 0; j < 4; ++j) acc1[i][j] = (f32x4){0.f, 0.f, 0.f, 0.f};
#pragma unroll
  for (int ks = 0; ks < 2; ++ks) {
    bf16x8 ah[4], al[4];
#pragma unroll
    for (int fm = 0; fm < 4; ++fm) {
      int idx = ((ks * 4 + l4) * 64 + fm * 16 + l15) * 8;
      ah[fm] = *(const bf16x8*)&featH[idx];
      al[fm] = *(const bf16x8*)&featL[idx];
    }
#pragma unroll
    for (int fn = 0; fn < 4; ++fn) {
      int col = wbase + fn * 16 + l15;
      size_t boff = ((size_t)(ks * 4 + l4) * 256 + col) * 8;
      bf16x8 bh = *(const bf16x8*)(lw1H + boff);
      bf16x8 bl = *(const bf16x8*)(lw1L + boff);
#pragma unroll
      for (int fm = 0; fm < 4; ++fm) {
        acc1[fm][fn] = __builtin_amdgcn_mfma_f32_16x16x32_bf16(al[fm], bh, acc1[fm][fn], 0, 0, 0);
        acc1[fm][fn] = __builtin_amdgcn_mfma_f32_16x16x32_bf16(ah[fm], bl, acc1[fm][fn], 0, 0, 0);
        acc1[fm][fn] = __builtin_amdgcn_mfma_f32_16x16x32_bf16(ah[fm], bh, acc1[fm][fn], 0, 0, 0);
      }
    }
  }
#pragma unroll
  for (int fn = 0; fn < 4; ++fn) {
    int chan = wbase + fn * 16 + l15;
    float bias = lb1[chan];
    int kb = chan >> 3, k7 = chan & 7;
#pragma unroll
    for (int fm = 0; fm < 4; ++fm) {
#pragma unroll
      for (int r = 0; r < 4; ++r) {
        int edge = fm * 16 + l4 * 4 + r;
        float v = fmaxf(acc1[fm][fn][r] + bias, 0.f);
        ushort hi = f2bf(v);
        ushort lo = f2bf(v - bf2f(hi));
        int idx = (kb * 64 + edge) * 8 + k7;
        t1H[idx] = hi;
        t1L[idx] = lo;
      }
    }
  }
  __syncthreads();
  const ushort* lw2H = lw2s;
  const ushort* lw2L = lw2s + 32 * 256 * 8;
  f32x4 acc2[4][4];
#pragma unroll
  for (int i = 0; i < 4; ++i)
#pragma unroll
    for (int j = 0; j < 4; ++j) acc2[i][j] = (f32x4){0.f, 0.f, 0.f, 0.f};
#pragma unroll
  for (int ks = 0; ks < 8; ++ks) {
    bf16x8 ah[4], al[4];
#pragma unroll
    for (int fm = 0; fm < 4; ++fm) {
      int idx = ((ks * 4 + l4) * 64 + fm * 16 + l15) * 8;
      ah[fm] = *(const bf16x8*)&t1H[idx];
      al[fm] = *(const bf16x8*)&t1L[idx];
    }
#pragma unroll
    for (int fn = 0; fn < 4; ++fn) {
      int col = wbase + fn * 16 + l15;
      size_t boff = ((size_t)(ks * 4 + l4) * 256 + col) * 8;
      bf16x8 bh = *(const bf16x8*)(lw2H + boff);
      bf16x8 bl = *(const bf16x8*)(lw2L + boff);
#pragma unroll
      for (int fm = 0; fm < 4; ++fm) {
        acc2[fm][fn] = __builtin_amdgcn_mfma_f32_16x16x32_bf16(al[fm], bh, acc2[fm][fn], 0, 0, 0);
        acc2[fm][fn] = __builtin_amdgcn_mfma_f32_16x16x32_bf16(ah[fm], bl, acc2[fm][fn], 0, 0, 0);
        acc2[fm][fn] = __builtin_amdgcn_mfma_f32_16x16x32_bf16(ah[fm], bh, acc2[fm][fn], 0, 0, 0);
      }
    }
  }
#pragma unroll
  for (int fn = 0; fn < 4; ++fn) {
    int col = wbase + fn * 16 + l15;
    float m0 = -INFINITY, m1 = -INFINITY;
#pragma unroll
    for (int r = 0; r < 4; ++r) {
      m0 = fmaxf(m0, fmaxf(acc2[0][fn][r], acc2[1][fn][r]));
      m1 = fmaxf(m1, fmaxf(acc2[2][fn][r], acc2[3][fn][r]));
    }
    m0 = fmaxf(m0, __shfl_xor(m0, 16));
    m0 = fmaxf(m0, __shfl_xor(m0, 32));
    m1 = fmaxf(m1, __shfl_xor(m1, 16));
    m1 = fmaxf(m1, __shfl_xor(m1, 32));
    if (l4 == 0) {
      float bias = lb2[col];
      int c0 = blockIdx.x * 2;
      split_store(m0 + bias, hH, hL, (size_t)c0 * 256 + col);
      split_store(m1 + bias, hH, hL, (size_t)(c0 + 1) * 256 + col);
    }
  }
}

// ---------------------------------------------------------------------------
// Split-plane MFMA GEMM (round-7 structure). ROUND-15 CHANGE: occupancy
// bump — BM=128 guarantees 3 waves/SIMD (VGPR cap 168), BM=64 guarantees
// 4 waves/SIMD (cap 128). Everything else identical to the 1986us baseline.
// ---------------------------------------------------------------------------
template <int EPI, int OUTS, int BM>
__global__ __launch_bounds__(256, (BM == 128 ? 3 : 4))
void gemm_s(const ushort* __restrict__ AH, const ushort* __restrict__ AL,
            const ushort* __restrict__ Wh, const ushort* __restrict__ Wl,
            const float* __restrict__ bias, const float* __restrict__ gamma,
            const float* __restrict__ resid, float* __restrict__ C,
            ushort* __restrict__ CH, ushort* __restrict__ CL,
            int M, int N, int K) {
  constexpr int FN = (BM == 128) ? 4 : 2;
  __shared__ __align__(16) ushort Ah[BM * 32], Al[BM * 32];
  __shared__ __align__(16) ushort Bh[4096], Bl[4096];
  int tid = threadIdx.x;
  int bn = blockIdx.x << 7, bm = blockIdx.y * BM;
  int wid = tid >> 6, lane = tid & 63;
  int wr = (BM == 128) ? (wid >> 1) : 0;
  int wc = (BM == 128) ? (wid & 1) : wid;
  int l15 = lane & 15, l4 = lane >> 4;

  int arow = (BM == 128) ? (tid >> 1) : (tid & 63);
  int akb0 = (BM == 128) ? ((tid & 1) << 1) : (tid >> 6);
  const ushort* ApH = AH + (size_t)(bm + arow) * K + akb0 * 8;
  const ushort* ApL = AL + (size_t)(bm + arow) * K + akb0 * 8;
  int wkb = tid >> 7, wn = tid & 127;

  f32x4 acc[4][FN];
#pragma unroll
  for (int i = 0; i < 4; ++i)
#pragma unroll
    for (int j = 0; j < FN; ++j) acc[i][j] = (f32x4){0.f, 0.f, 0.f, 0.f};

  uint4 aH0 = *(const uint4*)(ApH);
  uint4 aL0 = *(const uint4*)(ApL);
  uint4 aH1, aL1;
  if (BM == 128) {
    aH1 = *(const uint4*)(ApH + 8);
    aL1 = *(const uint4*)(ApL + 8);
  }
  size_t wo1 = ((size_t)wkb * N + bn + wn) * 8;
  size_t wo2 = ((size_t)(wkb + 2) * N + bn + wn) * 8;
  uint4 w0 = *(const uint4*)(Wh + wo1);
  uint4 w1 = *(const uint4*)(Wh + wo2);
  uint4 w2 = *(const uint4*)(Wl + wo1);
  uint4 w3 = *(const uint4*)(Wl + wo2);

  int nkt = K >> 5;
  for (int kt = 0; kt < nkt; ++kt) {
    if (BM == 128) {
      *(uint4*)&Ah[(akb0 * 128 + arow) * 8] = aH0;
      *(uint4*)&Ah[((akb0 + 1) * 128 + arow) * 8] = aH1;
      *(uint4*)&Al[(akb0 * 128 + arow) * 8] = aL0;
      *(uint4*)&Al[((akb0 + 1) * 128 + arow) * 8] = aL1;
    } else {
      *(uint4*)&Ah[(akb0 * 64 + arow) * 8] = aH0;
      *(uint4*)&Al[(akb0 * 64 + arow) * 8] = aL0;
    }
    *(uint4*)&Bh[tid * 8] = w0;
    *(uint4*)&Bh[(tid + 256) * 8] = w1;
    *(uint4*)&Bl[tid * 8] = w2;
    *(uint4*)&Bl[(tid + 256) * 8] = w3;
    __syncthreads();
    if (kt + 1 < nkt) {
      aH0 = *(const uint4*)(ApH + (kt + 1) * 32);
      aL0 = *(const uint4*)(ApL + (kt + 1) * 32);
      if (BM == 128) {
        aH1 = *(const uint4*)(ApH + (kt + 1) * 32 + 8);
        aL1 = *(const uint4*)(ApL + (kt + 1) * 32 + 8);
      }
      size_t b1 = ((size_t)((kt + 1) * 4 + wkb) * N + bn + wn) * 8;
      size_t b2 = ((size_t)((kt + 1) * 4 + wkb + 2) * N + bn + wn) * 8;
      w0 = *(const uint4*)(Wh + b1);
      w1 = *(const uint4*)(Wh + b2);
      w2 = *(const uint4*)(Wl + b1);
      w3 = *(const uint4*)(Wl + b2);
    }
    bf16x8 ahf[4], alf[4];
#pragma unroll
    for (int fm = 0; fm < 4; ++fm) {
      int ci = l4 * BM + wr * 64 + fm * 16 + l15;
      ahf[fm] = *(bf16x8*)&Ah[ci * 8];
      alf[fm] = *(bf16x8*)&Al[ci * 8];
    }
#pragma unroll
    for (int fn = 0; fn < FN; ++fn) {
      int ci = l4 * 128 + wc * (FN * 16) + fn * 16 + l15;
      bf16x8 bh = *(bf16x8*)&Bh[ci * 8];
      bf16x8 bl = *(bf16x8*)&Bl[ci * 8];
#pragma unroll
      for (int fm = 0; fm < 4; ++fm) {
        acc[fm][fn] = __builtin_amdgcn_mfma_f32_16x16x32_bf16(alf[fm], bh, acc[fm][fn], 0, 0, 0);
        acc[fm][fn] = __builtin_amdgcn_mfma_f32_16x16x32_bf16(ahf[fm], bl, acc[fm][fn], 0, 0, 0);
        acc[fm][fn] = __builtin_amdgcn_mfma_f32_16x16x32_bf16(ahf[fm], bh, acc[fm][fn], 0, 0, 0);
      }
    }
    __syncthreads();
  }

#pragma unroll
  for (int fn = 0; fn < FN; ++fn) {
    int col = bn + wc * (FN * 16) + fn * 16 + l15;
    float bv = bias[col];
    float gv = (EPI == 3) ? gamma[col] : 0.f;
#pragma unroll
    for (int fm = 0; fm < 4; ++fm) {
      int row0 = bm + wr * 64 + fm * 16 + l4 * 4;
#pragma unroll
      for (int r = 0; r < 4; ++r) {
        float v = acc[fm][fn][r] + bv;
        if (EPI == 1) v = fmaxf(v, 0.f);
        else if (EPI == 2) v = gelu_f(v);
        else if (EPI == 3) v = resid[(size_t)(row0 + r) * N + col] + gv * v;
        size_t off = (size_t)(row0 + r) * N + col;
        if (OUTS == 0) C[off] = v;
        else split_store(v, CH, CL, off);
      }
    }
  }
}

// ---------------------------------------------------------------------------
// Positional-embedding add (unchanged).
// ---------------------------------------------------------------------------
__global__ __launch_bounds__(256)
void pe_add(const float* __restrict__ centers, const float* __restrict__ ew,
            const float* __restrict__ eb, float* x) {
  __shared__ float fc[51];
  int c = blockIdx.x, tid = threadIdx.x;
  if (tid < 24) {
    int a = tid >> 3, f = tid & 7;
    float coord = centers[c * 3 + a];
    float p = coord * (float)(M_PI * (double)(1 << f));
    fc[3 + tid] = sinf(p);
    fc[27 + tid] = cosf(p);
  } else if (tid < 27) {
    fc[tid - 24] = centers[c * 3 + (tid - 24)];
  }
  __syncthreads();
  for (int j = tid; j < NDIM; j += 256) {
    float acc = eb[j];
#pragma unroll
    for (int d = 0; d < 51; ++d) acc = fmaf(fc[d], ew[d * NDIM + j], acc);
    x[(size_t)c * NDIM + j] += acc;
  }
}

// ---------------------------------------------------------------------------
// LayerNorm fp32-out (final) and split-out (in-loop).
// ---------------------------------------------------------------------------
__global__ __launch_bounds__(256)
void ln_f32(const float* __restrict__ x, const float* __restrict__ g,
            const float* __restrict__ b, float* __restrict__ y) {
  int row = (blockIdx.x << 2) + (threadIdx.x >> 6);
  int lane = threadIdx.x & 63;
  const float* xr = x + (size_t)row * NDIM;
  float v[6];
#pragma unroll
  for (int i = 0; i < 6; ++i) v[i] = xr[lane + (i << 6)];
  float s = 0.f;
#pragma unroll
  for (int i = 0; i < 6; ++i) s += v[i];
#pragma unroll
  for (int off = 32; off; off >>= 1) s += __shfl_xor(s, off);
  float m = s / 384.f;
  float var = 0.f;
#pragma unroll
  for (int i = 0; i < 6; ++i) { float dd = v[i] - m; var += dd * dd; }
#pragma unroll
  for (int off = 32; off; off >>= 1) var += __shfl_xor(var, off);
  var = var / 384.f;
  float rs = 1.f / sqrtf(var + 1e-6f);
#pragma unroll
  for (int i = 0; i < 6; ++i) {
    int cc = lane + (i << 6);
    y[(size_t)row * NDIM + cc] = (v[i] - m) * rs * g[cc] + b[cc];
  }
}

__global__ __launch_bounds__(256)
void ln_split(const float* __restrict__ x, const float* __restrict__ g,
              const float* __restrict__ b, ushort* __restrict__ yH,
              ushort* __restrict__ yL) {
  int row = (blockIdx.x << 2) + (threadIdx.x >> 6);
  int lane = threadIdx.x & 63;
  const float* xr = x + (size_t)row * NDIM;
  float v[6];
#pragma unroll
  for (int i = 0; i < 6; ++i) v[i] = xr[lane + (i << 6)];
  float s = 0.f;
#pragma unroll
  for (int i = 0; i < 6; ++i) s += v[i];
#pragma unroll
  for (int off = 32; off; off >>= 1) s += __shfl_xor(s, off);
  float m = s / 384.f;
  float var = 0.f;
#pragma unroll
  for (int i = 0; i < 6; ++i) { float dd = v[i] - m; var += dd * dd; }
#pragma unroll
  for (int off = 32; off; off >>= 1) var += __shfl_xor(var, off);
  var = var / 384.f;
  float rs = 1.f / sqrtf(var + 1e-6f);
#pragma unroll
  for (int i = 0; i < 6; ++i) {
    int cc = lane + (i << 6);
    float yv = (v[i] - m) * rs * g[cc] + b[cc];
    split_store(yv, yH, yL, (size_t)row * NDIM + cc);
  }
}

// ---------------------------------------------------------------------------
// MFMA flash attention on split planes (unchanged).
// ---------------------------------------------------------------------------
__global__ __launch_bounds__(256, 2)
void attn_mfma(const ushort* __restrict__ FH, const ushort* __restrict__ FL,
               ushort* __restrict__ oH, ushort* __restrict__ oL) {
  __shared__ __align__(16) ushort kTH[4096], kTL[4096];
  __shared__ __align__(16) ushort vSH[4096], vSL[4096];
  __shared__ __align__(16) ushort pSH[8192], pSL[8192];
  int bi = blockIdx.x;
  int qt = bi & 3;
  int hh = (bi >> 2) % 6;
  int b = bi / 24;
  int tid = threadIdx.x;
  int w = tid >> 6, lane = tid & 63;
  int l15 = lane & 15, l4 = lane >> 4;
  const ushort* baseH = FH + (size_t)(b * NCTR) * 1152;
  const ushort* baseL = FL + (size_t)(b * NCTR) * 1152;
  int qbase = qt * 128 + w * 32;

  bf16x8 qh[2][2], ql[2][2];
#pragma unroll
  for (int qr = 0; qr < 2; ++qr) {
#pragma unroll
    for (int ds = 0; ds < 2; ++ds) {
      size_t off = (size_t)(qbase + qr * 16 + l15) * 1152 + hh * 64 + ds * 32 + l4 * 8;
      qh[qr][ds] = *(const bf16x8*)(baseH + off);
      ql[qr][ds] = *(const bf16x8*)(baseL + off);
    }
  }

  f32x4 oacc[2][4];
#pragma unroll
  for (int i = 0; i < 2; ++i)
#pragma unroll
    for (int j = 0; j < 4; ++j) oacc[i][j] = (f32x4){0.f, 0.f, 0.f, 0.f};
  float m_[2][4], l_[2][4];
#pragma unroll
  for (int i = 0; i < 2; ++i)
#pragma unroll
    for (int r = 0; r < 4; ++r) { m_[i][r] = -INFINITY; l_[i][r] = 0.f; }

  ushort* pHw = pSH + w * 2048;
  ushort* pLw = pSL + w * 2048;

  for (int ch = 0; ch < 8; ++ch) {
    {
      int key = tid & 63, dgh = tid >> 6;
      size_t krow = (size_t)(ch * 64 + key) * 1152 + 384 + hh * 64;
#pragma unroll
      for (int i = 0; i < 2; ++i) {
        int dg = dgh * 2 + i;
        *(uint4*)&kTH[(dg * 64 + key) * 8] = *(const uint4*)(baseH + krow + dg * 8);
        *(uint4*)&kTL[(dg * 64 + key) * 8] = *(const uint4*)(baseL + krow + dg * 8);
      }
      int d = tid & 63, kb2 = tid >> 6;
#pragma unroll
      for (int i = 0; i < 2; ++i) {
        int kb = kb2 + i * 4;
        ushort hv[8], lv[8];
#pragma unroll
        for (int j = 0; j < 8; ++j) {
          size_t off = (size_t)(ch * 64 + kb * 8 + j) * 1152 + 768 + hh * 64 + d;
          hv[j] = baseH[off];
          lv[j] = baseL[off];
        }
        uint4 H, L;
        H.x = (uint)hv[0] | ((uint)hv[1] << 16); H.y = (uint)hv[2] | ((uint)hv[3] << 16);
        H.z = (uint)hv[4] | ((uint)hv[5] << 16); H.w = (uint)hv[6] | ((uint)hv[7] << 16);
        L.x = (uint)lv[0] | ((uint)lv[1] << 16); L.y = (uint)lv[2] | ((uint)lv[3] << 16);
        L.z = (uint)lv[4] | ((uint)lv[5] << 16); L.w = (uint)lv[6] | ((uint)lv[7] << 16);
        *(uint4*)&vSH[(kb * 64 + d) * 8] = H;
        *(uint4*)&vSL[(kb * 64 + d) * 8] = L;
      }
    }
    __syncthreads();

    f32x4 sacc[2][4];
#pragma unroll
    for (int i = 0; i < 2; ++i)
#pragma unroll
      for (int j = 0; j < 4; ++j) sacc[i][j] = (f32x4){0.f, 0.f, 0.f, 0.f};
#pragma unroll
    for (int ds = 0; ds < 2; ++ds) {
#pragma unroll
      for (int kc = 0; kc < 4; ++kc) {
        int idx = ((ds * 4 + l4) * 64 + kc * 16 + l15) * 8;
        bf16x8 bh = *(const bf16x8*)&kTH[idx];
        bf16x8 bl = *(const bf16x8*)&kTL[idx];
#pragma unroll
        for (int qr = 0; qr < 2; ++qr) {
          sacc[qr][kc] = __builtin_amdgcn_mfma_f32_16x16x32_bf16(ql[qr][ds], bh, sacc[qr][kc], 0, 0, 0);
          sacc[qr][kc] = __builtin_amdgcn_mfma_f32_16x16x32_bf16(qh[qr][ds], bl, sacc[qr][kc], 0, 0, 0);
          sacc[qr][kc] = __builtin_amdgcn_mfma_f32_16x16x32_bf16(qh[qr][ds], bh, sacc[qr][kc], 0, 0, 0);
        }
      }
    }

    float t[2][4];
#pragma unroll
    for (int qr = 0; qr < 2; ++qr)
#pragma unroll
      for (int r = 0; r < 4; ++r) {
        float a0 = sacc[qr][0][r] * 0.125f; sacc[qr][0][r] = a0;
        float a1 = sacc[qr][1][r] * 0.125f; sacc[qr][1][r] = a1;
        float a2 = sacc[qr][2][r] * 0.125f; sacc[qr][2][r] = a2;
        float a3 = sacc[qr][3][r] * 0.125f; sacc[qr][3][r] = a3;
        t[qr][r] = fmaxf(fmaxf(a0, a1), fmaxf(a2, a3));
      }
#pragma unroll
    for (int off = 1; off < 16; off <<= 1)
#pragma unroll
      for (int qr = 0; qr < 2; ++qr)
#pragma unroll
        for (int r = 0; r < 4; ++r)
          t[qr][r] = fmaxf(t[qr][r], __shfl_xor(t[qr][r], off));
    float f_[2][4];
#pragma unroll
    for (int qr = 0; qr < 2; ++qr)
#pragma unroll
      for (int r = 0; r < 4; ++r) {
        float mn = fmaxf(m_[qr][r], t[qr][r]);
        f_[qr][r] = expf(m_[qr][r] - mn);
        m_[qr][r] = mn;
      }
#pragma unroll
    for (int qr = 0; qr < 2; ++qr)
#pragma unroll
      for (int dc = 0; dc < 4; ++dc)
#pragma unroll
        for (int r = 0; r < 4; ++r) oacc[qr][dc][r] *= f_[qr][r];
    float sm[2][4];
#pragma unroll
    for (int qr = 0; qr < 2; ++qr)
#pragma unroll
      for (int r = 0; r < 4; ++r) {
        float p0 = expf(sacc[qr][0][r] - m_[qr][r]); sacc[qr][0][r] = p0;
        float p1 = expf(sacc[qr][1][r] - m_[qr][r]); sacc[qr][1][r] = p1;
        float p2 = expf(sacc[qr][2][r] - m_[qr][r]); sacc[qr][2][r] = p2;
        float p3 = expf(sacc[qr][3][r] - m_[qr][r]); sacc[qr][3][r] = p3;
        sm[qr][r] = ((p0 + p1) + (p2 + p3));
      }
#pragma unroll
    for (int off = 1; off < 16; off <<= 1)
#pragma unroll
      for (int qr = 0; qr < 2; ++qr)
#pragma unroll
        for (int r = 0; r < 4; ++r)
          sm[qr][r] += __shfl_xor(sm[qr][r], off);
#pragma unroll
    for (int qr = 0; qr < 2; ++qr)
#pragma unroll
      for (int r = 0; r < 4; ++r) l_[qr][r] = l_[qr][r] * f_[qr][r] + sm[qr][r];

#pragma unroll
    for (int qr = 0; qr < 2; ++qr)
#pragma unroll
      for (int kc = 0; kc < 4; ++kc)
#pragma unroll
        for (int r = 0; r < 4; ++r) {
          float pv = sacc[qr][kc][r];
          ushort hi = f2bf(pv);
          ushort lo = f2bf(pv - bf2f(hi));
          int k = kc * 16 + l15;
          int qrow = qr * 16 + l4 * 4 + r;
          int idx = ((k >> 3) * 32 + qrow) * 8 + (k & 7);
          pHw[idx] = hi;
          pLw[idx] = lo;
        }

#pragma unroll
    for (int ks = 0; ks < 2; ++ks) {
      bf16x8 pah[2], pal[2];
#pragma unroll
      for (int qr = 0; qr < 2; ++qr) {
        int idx = ((ks * 4 + l4) * 32 + qr * 16 + l15) * 8;
        pah[qr] = *(const bf16x8*)&pHw[idx];
        pal[qr] = *(const bf16x8*)&pLw[idx];
      }
#pragma unroll
      for (int dc = 0; dc < 4; ++dc) {
        int idx = ((ks * 4 + l4) * 64 + dc * 16 + l15) * 8;
        bf16x8 vh = *(const bf16x8*)&vSH[idx];
        bf16x8 vl = *(const bf16x8*)&vSL[idx];
#pragma unroll
        for (int qr = 0; qr < 2; ++qr) {
          oacc[qr][dc] = __builtin_amdgcn_mfma_f32_16x16x32_bf16(pal[qr], vh, oacc[qr][dc], 0, 0, 0);
          oacc[qr][dc] = __builtin_amdgcn_mfma_f32_16x16x32_bf16(pah[qr], vl, oacc[qr][dc], 0, 0, 0);
          oacc[qr][dc] = __builtin_amdgcn_mfma_f32_16x16x32_bf16(pah[qr], vh, oacc[qr][dc], 0, 0, 0);
        }
      }
    }
    __syncthreads();
  }

  float il[2][4];
#pragma unroll
  for (int qr = 0; qr < 2; ++qr)
#pragma unroll
    for (int r = 0; r < 4; ++r) il[qr][r] = 1.f / l_[qr][r];
#pragma unroll
  for (int qr = 0; qr < 2; ++qr)
#pragma unroll
    for (int dc = 0; dc < 4; ++dc)
#pragma unroll
      for (int r = 0; r < 4; ++r) {
        int row = b * NCTR + qbase + qr * 16 + l4 * 4 + r;
        int col = hh * 64 + dc * 16 + l15;
        split_store(oacc[qr][dc][r] * il[qr][r], oH, oL, (size_t)row * NDIM + col);
      }
}

// ---------------------------------------------------------------------------
extern "C" void kernel_launch(void* const* d_in, const int* in_sizes, int n_in,
                              void* d_out, int out_size, void* d_ws, size_t ws_size,
                              hipStream_t stream) {
  const float* pc      = (const float*)d_in[0];
  const float* embed_w = (const float*)d_in[1];
  const float* embed_b = (const float*)d_in[2];
  const float* lw1     = (const float*)d_in[3];
  const float* lb1     = (const float*)d_in[4];
  const float* lw2     = (const float*)d_in[5];
  const float* lb2     = (const float*)d_in[6];
  const float* gw1     = (const float*)d_in[7];
  const float* gb1     = (const float*)d_in[8];
  const float* gw2     = (const float*)d_in[9];
  const float* gb2     = (const float*)d_in[10];
  const float* ln1_g   = (const float*)d_in[11];
  const float* ln1_b   = (const float*)d_in[12];
  const float* qkv_w   = (const float*)d_in[13];
  const float* qkv_b   = (const float*)d_in[14];
  const float* proj_w  = (const float*)d_in[15];
  const float* proj_b  = (const float*)d_in[16];
  const float* gamma1  = (const float*)d_in[17];
  const float* ln2_g   = (const float*)d_in[18];
  const float* ln2_b   = (const float*)d_in[19];
  const float* fc1_w   = (const float*)d_in[20];
  const float* fc1_b   = (const float*)d_in[21];
  const float* fc2_w   = (const float*)d_in[22];
  const float* fc2_b   = (const float*)d_in[23];
  const float* gamma2  = (const float*)d_in[24];
  const float* lnf_g   = (const float*)d_in[25];
  const float* lnf_b   = (const float*)d_in[26];

  float* out = (float*)d_out;
  float* centers = out + (size_t)NB * NCTR * NDIM;

  char* ws = (char*)d_ws;
  int*    nn  = (int*)(ws + 0);
  float*  x   = (float*)(ws + 1048576);
  ushort* xnH = (ushort*)(ws + 13631488);
  ushort* xnL = (ushort*)(ws + 19922944);
  ushort* FH  = (ushort*)(ws + 26214400);
  ushort* FL  = (ushort*)(ws + 51380224);
  ushort* hH  = (ushort*)(ws + 76546048);
  ushort* hL  = (ushort*)(ws + 80740352);
  ushort* wsplit = (ushort*)(ws + 84934656);

  // --- weight pre-split descriptor (runs merged with FPS) ---
  WAll wa;
  const float* srcs[8] = {qkv_w, proj_w, fc1_w, fc2_w, gw1, gw2, lw1, lw2};
  int kpads[8] = {2304, 2304, 2304, 9216, 256, 256, 64, 256};
  int ns[8]    = {1152, 384, 1536, 384, 256, 384, 256, 256};
  int ksrcs[8] = {2304, 2304, 2304, 9216, 256, 256, 51, 256};
  ushort* dsts[8];
  size_t wofs = 0;
  int cum = 0;
  for (int f = 0; f < 8; ++f) {
    dsts[f] = wsplit + wofs;
    wofs += (size_t)2 * kpads[f] * ns[f];
    wa.src[f] = srcs[f];
    wa.dst[f] = dsts[f];
    wa.K8[f] = kpads[f] >> 3;
    wa.N[f] = ns[f];
    wa.Ksrc[f] = ksrcs[f];
    wa.blk0[f] = cum;
    cum += ((kpads[f] >> 3) * ns[f] + 255) / 256;
  }
  wa.blk0[8] = cum;
  ushort* qkvS = dsts[0];
  ushort* projS = dsts[1];
  ushort* fc1S = dsts[2];
  ushort* fc2S = dsts[3];
  ushort* g1S = dsts[4];
  ushort* g2S = dsts[5];
  ushort* lw1s = dsts[6];
  ushort* lw2s = dsts[7];

  // --- FPS (blocks 0..15) + weight split (rest) in one launch ---
  fps_wconv<<<16 + cum, 256, 0, stream>>>(pc, centers, wa);
  knn_kernel<<<2048, 256, 0, stream>>>(pc, centers, nn);
  edge_mfma<<<4096, 256, 0, stream>>>(pc, centers, nn, lw1s, lb1, lw2s, lb2, hH, hL);

  gemm_s<1, 1, 64><<<dim3(2, 128), 256, 0, stream>>>(
      hH, hL, g1S, g1S + 65536, gb1, nullptr, nullptr, nullptr, xnH, xnL,
      8192, 256, 256);
  gemm_s<0, 0, 64><<<dim3(3, 128), 256, 0, stream>>>(
      xnH, xnL, g2S, g2S + 98304, gb2, nullptr, nullptr, x, nullptr, nullptr,
      8192, 384, 256);
  pe_add<<<8192, 256, 0, stream>>>(centers, embed_w, embed_b, x);

  for (int l = 0; l < 6; ++l) {
    ln_split<<<2048, 256, 0, stream>>>(x, ln1_g + l * 384, ln1_b + l * 384, xnH, xnL);
    gemm_s<0, 1, 128><<<dim3(9, 64), 256, 0, stream>>>(
        xnH, xnL, qkvS + (size_t)l * 442368, qkvS + 2654208 + (size_t)l * 442368,
        qkv_b + l * 1152, nullptr, nullptr, nullptr, FH, FL, 8192, 1152, 384);
    attn_mfma<<<384, 256, 0, stream>>>(FH, FL, xnH, xnL);
    gemm_s<3, 0, 64><<<dim3(3, 128), 256, 0, stream>>>(
        xnH, xnL, projS + (size_t)l * 147456, projS + 884736 + (size_t)l * 147456,
        proj_b + l * 384, gamma1 + l * 384, x, x, nullptr, nullptr, 8192, 384, 384);
    ln_split<<<2048, 256, 0, stream>>>(x, ln2_g + l * 384, ln2_b + l * 384, xnH, xnL);
    gemm_s<2, 1, 128><<<dim3(12, 64), 256, 0, stream>>>(
        xnH, xnL, fc1S + (size_t)l * 589824, fc1S + 3538944 + (size_t)l * 589824,
        fc1_b + l * 1536, nullptr, nullptr, nullptr, FH, FL, 8192, 1536, 384);
    gemm_s<3, 0, 64><<<dim3(3, 128), 256, 0, stream>>>(
        FH, FL, fc2S + (size_t)l * 589824, fc2S + 3538944 + (size_t)l * 589824,
        fc2_b + l * 384, gamma2 + l * 384, x, x, nullptr, nullptr, 8192, 384, 1536);
  }
  ln_f32<<<2048, 256, 0, stream>>>(x, lnf_g, lnf_b, out);
}

// Round 16
// 1981.228 us; speedup vs baseline: 1.0147x; 1.0147x over previous
//
#include <hip/hip_runtime.h>
#include <math.h>

#define NB 16
#define NM 2048
#define NCTR 512
#define NK 32
#define NDIM 384

typedef unsigned long long ull;
typedef unsigned int uint;
typedef unsigned short ushort;
typedef __attribute__((ext_vector_type(8))) short bf16x8;
typedef __attribute__((ext_vector_type(4))) float f32x4;

// Exact (no-FMA-contraction) squared distance, matching XLA's per-op fp32.
__device__ __forceinline__ float dist2_exact(float ax, float ay, float az,
                                             float bx, float by, float bz) {
  float dx = __fsub_rn(ax, bx);
  float dy = __fsub_rn(ay, by);
  float dz = __fsub_rn(az, bz);
  return __fadd_rn(__fadd_rn(__fmul_rn(dx, dx), __fmul_rn(dy, dy)),
                   __fmul_rn(dz, dz));
}

__device__ __forceinline__ float gelu_f(float x) {
  return 0.5f * x * (1.0f + erff(x * 0.70710678118654752f));
}

// fp32 -> bf16 round-to-nearest-even (bit trick), and back.
__device__ __forceinline__ ushort f2bf(float f) {
  uint u = __float_as_uint(f);
  return (ushort)((u + 0x7FFFu + ((u >> 16) & 1u)) >> 16);
}
__device__ __forceinline__ float bf2f(ushort h) {
  return __uint_as_float(((uint)h) << 16);
}

// Split 8 fp32 into bf16 hi / lo packed words (2 bf16 per uint).
__device__ __forceinline__ void cvt8(float4 p, float4 q, uint4& hi, uint4& lo) {
  float v0 = p.x, v1 = p.y, v2 = p.z, v3 = p.w;
  float v4 = q.x, v5 = q.y, v6 = q.z, v7 = q.w;
  ushort h0 = f2bf(v0), h1 = f2bf(v1), h2 = f2bf(v2), h3 = f2bf(v3);
  ushort h4 = f2bf(v4), h5 = f2bf(v5), h6 = f2bf(v6), h7 = f2bf(v7);
  ushort l0 = f2bf(v0 - bf2f(h0)), l1 = f2bf(v1 - bf2f(h1));
  ushort l2 = f2bf(v2 - bf2f(h2)), l3 = f2bf(v3 - bf2f(h3));
  ushort l4 = f2bf(v4 - bf2f(h4)), l5 = f2bf(v5 - bf2f(h5));
  ushort l6 = f2bf(v6 - bf2f(h6)), l7 = f2bf(v7 - bf2f(h7));
  hi.x = (uint)h0 | ((uint)h1 << 16); hi.y = (uint)h2 | ((uint)h3 << 16);
  hi.z = (uint)h4 | ((uint)h5 << 16); hi.w = (uint)h6 | ((uint)h7 << 16);
  lo.x = (uint)l0 | ((uint)l1 << 16); lo.y = (uint)l2 | ((uint)l3 << 16);
  lo.z = (uint)l4 | ((uint)l5 << 16); lo.w = (uint)l6 | ((uint)l7 << 16);
}

__device__ __forceinline__ void split_store(float v, ushort* H, ushort* L,
                                            size_t off) {
  ushort hi = f2bf(v);
  H[off] = hi;
  L[off] = f2bf(v - bf2f(hi));
}

// ---------------------------------------------------------------------------
// Combined weight pre-split descriptor.
// ---------------------------------------------------------------------------
struct WAll {
  const float* src[8];
  ushort* dst[8];
  int K8[8];
  int N[8];
  int Ksrc[8];
  int blk0[9];
};

// ---------------------------------------------------------------------------
// Merged FPS + weight-split (best: 256 threads, 4-wave FPS, 8 pts/lane —
// spill-free at VGPR_Count 52; fps floor ~310us, serial-latency bound).
// ---------------------------------------------------------------------------
__global__ __launch_bounds__(256)
void fps_wconv(const float* __restrict__ pc, float* __restrict__ centers,
               WAll a) {
  __shared__ float4 pos4[NM];
  __shared__ ull red[2][4];
  if (blockIdx.x >= 16) {
    int bid = blockIdx.x - 16;
    int f = 0;
#pragma unroll
    for (int i = 1; i < 8; ++i) f += (bid >= a.blk0[i]);
    int K8 = a.K8[f], N = a.N[f], Ksrc = a.Ksrc[f];
    int c = (bid - a.blk0[f]) * 256 + threadIdx.x;
    if (c >= K8 * N) return;
    const float* W = a.src[f];
    ushort* out = a.dst[f];
    int kb = c / N, n = c - kb * N;
    float v[8];
#pragma unroll
    for (int i = 0; i < 8; ++i) {
      int row = kb * 8 + i;
      v[i] = (row < Ksrc) ? W[(size_t)row * N + n] : 0.f;
    }
    float4 p, q;
    p.x = v[0]; p.y = v[1]; p.z = v[2]; p.w = v[3];
    q.x = v[4]; q.y = v[5]; q.z = v[6]; q.w = v[7];
    uint4 hi, lo;
    cvt8(p, q, hi, lo);
    *(uint4*)(out + (size_t)c * 8) = hi;
    *(uint4*)(out + (size_t)(K8 * N + c) * 8) = lo;
    return;
  }
  int b = blockIdx.x;
  const float* pb = pc + (size_t)b * (NM * 3);
  int tid = threadIdx.x, lane = tid & 63, wv = tid >> 6;
  float px[8], py[8], pz[8];
#pragma unroll
  for (int i = 0; i < 8; ++i) {
    int p = tid + 256 * i;
    float x = pb[3 * p], y = pb[3 * p + 1], z = pb[3 * p + 2];
    px[i] = x; py[i] = y; pz[i] = z;
    pos4[p] = make_float4(x, y, z, 0.f);
  }
  __syncthreads();
  float* cb = centers + (size_t)b * (NCTR * 3);
  float4 s0 = pos4[0];
  float sx = s0.x, sy = s0.y, sz = s0.z;
  if (tid == 0) { cb[0] = sx; cb[1] = sy; cb[2] = sz; }
  float d[8];
  for (int n = 1; n < NCTR; ++n) {
    ull best = 0;
#pragma unroll
    for (int i = 0; i < 8; ++i) {
      int p = tid + 256 * i;
      float nd = dist2_exact(px[i], py[i], pz[i], sx, sy, sz);
      d[i] = (n == 1) ? nd : fminf(d[i], nd);
      ull key = ((ull)__float_as_uint(d[i]) << 32) | (unsigned)(0x7FFFFFFF - p);
      best = best > key ? best : key;
    }
    float dl = __uint_as_float((uint)(best >> 32));
    float wm = dl;
#pragma unroll
    for (int off = 32; off; off >>= 1) wm = fmaxf(wm, __shfl_xor(wm, off));
    ull mask = __ballot(dl == wm);
    ull wkey;
    if (mask & (mask - 1)) {
      wkey = best;
#pragma unroll
      for (int off = 32; off; off >>= 1) {
        ull o = __shfl_xor(wkey, off);
        wkey = wkey > o ? wkey : o;
      }
    } else {
      int src = __ffsll((long long)mask) - 1;
      wkey = __shfl(best, src);
    }
    if (lane == 0) red[n & 1][wv] = wkey;
    __syncthreads();
    ull g0 = red[n & 1][0], g1 = red[n & 1][1];
    ull g2 = red[n & 1][2], g3 = red[n & 1][3];
    ull ga = g0 > g1 ? g0 : g1;
    ull gc2 = g2 > g3 ? g2 : g3;
    ull gb = ga > gc2 ? ga : gc2;
    int j = 0x7FFFFFFF - (int)(unsigned)(gb & 0xFFFFFFFFull);
    float4 np = pos4[j];
    sx = np.x; sy = np.y; sz = np.z;
    if (tid == 0) { cb[n * 3] = sx; cb[n * 3 + 1] = sy; cb[n * 3 + 2] = sz; }
  }
}

// ---------------------------------------------------------------------------
// KNN v2 (spill-free).
// ---------------------------------------------------------------------------
__global__ __launch_bounds__(256, 2)
void knn_kernel(const float* __restrict__ pc, const float* __restrict__ centers,
                int* __restrict__ nn) {
  __shared__ float pos[NM * 3];
  int b = blockIdx.x >> 7;
  int n0 = (blockIdx.x & 127) << 2;
  const float* pb = pc + (size_t)b * (NM * 3);
  for (int i = threadIdx.x; i < NM * 3; i += 256) pos[i] = pb[i];
  __syncthreads();
  int wv = threadIdx.x >> 6, lane = threadIdx.x & 63;
  int gc = b * NCTR + n0 + wv;
  float cx = centers[gc * 3], cy = centers[gc * 3 + 1], cz = centers[gc * 3 + 2];
  ull key[32];
  ull gmin[4];
#pragma unroll
  for (int g = 0; g < 4; ++g) {
    gmin[g] = ~0ull;
#pragma unroll
    for (int i = 0; i < 8; ++i) {
      int r = g * 8 + i;
      int p = lane + (r << 6);
      float nd = dist2_exact(pos[3 * p], pos[3 * p + 1], pos[3 * p + 2], cx, cy, cz);
      key[r] = ((ull)__float_as_uint(nd) << 11) | (unsigned)p;
      gmin[g] = gmin[g] < key[r] ? gmin[g] : key[r];
    }
  }
  ull a01 = gmin[0] < gmin[1] ? gmin[0] : gmin[1];
  ull a23 = gmin[2] < gmin[3] ? gmin[2] : gmin[3];
  ull lmin = a01 < a23 ? a01 : a23;
  int* nnc = nn + (size_t)gc * NK;
  for (int round = 0; round < NK; ++round) {
    ull w = lmin;
#pragma unroll
    for (int off = 32; off; off >>= 1) {
      ull o = __shfl_xor(w, off);
      w = w < o ? w : o;
    }
    if (lmin == w) {
      nnc[round] = (int)(w & 2047ull);
#pragma unroll
      for (int g = 0; g < 4; ++g) {
        if (gmin[g] == w) {
          gmin[g] = ~0ull;
#pragma unroll
          for (int i = 0; i < 8; ++i) {
            int r = g * 8 + i;
            key[r] = (key[r] == w) ? ~0ull : key[r];
            gmin[g] = gmin[g] < key[r] ? gmin[g] : key[r];
          }
        }
      }
      ull b01 = gmin[0] < gmin[1] ? gmin[0] : gmin[1];
      ull b23 = gmin[2] < gmin[3] ? gmin[2] : gmin[3];
      lmin = b01 < b23 ? b01 : b23;
    }
  }
}

// ---------------------------------------------------------------------------
// Fused edge pipeline.
// ---------------------------------------------------------------------------
__global__ __launch_bounds__(256, 2)
void edge_mfma(const float* __restrict__ pc, const float* __restrict__ centers,
               const int* __restrict__ nn, const ushort* __restrict__ lw1s,
               const float* __restrict__ lb1, const ushort* __restrict__ lw2s,
               const float* __restrict__ lb2, ushort* __restrict__ hH,
               ushort* __restrict__ hL) {
  __shared__ __align__(16) ushort featH[4096], featL[4096];
  __shared__ __align__(16) ushort t1H[16384], t1L[16384];
  int tid = threadIdx.x;
  int w = tid >> 6, lane = tid & 63;
  int l15 = lane & 15, l4 = lane >> 4;
  int wbase = w << 6;
  {
    int e = tid >> 2, s = tid & 3;
    int ge = blockIdx.x * 64 + e;
    int c = ge >> 5;
    int b = c >> 9;
    int j = nn[ge];
    const float* sp = pc + ((size_t)b * NM + j) * 3;
    float rx = sp[0] - centers[c * 3];
    float ry = sp[1] - centers[c * 3 + 1];
    float rz = sp[2] - centers[c * 3 + 2];
    auto putk = [&](int k, float v) {
      ushort hi = f2bf(v);
      ushort lo = f2bf(v - bf2f(hi));
      int idx = ((k >> 3) * 64 + e) * 8 + (k & 7);
      featH[idx] = hi;
      featL[idx] = lo;
    };
    if (s < 3) {
      float r = (s == 0) ? rx : (s == 1) ? ry : rz;
#pragma unroll
      for (int f = 0; f < 8; ++f) {
        float ef = (float)(M_PI * (double)(1 << f));
        float p = r * ef;
        putk(3 + 8 * s + f, sinf(p));
        putk(27 + 8 * s + f, cosf(p));
      }
    } else {
      putk(0, rx);
      putk(1, ry);
      putk(2, rz);
#pragma unroll
      for (int k = 51; k < 64; ++k) putk(k, 0.f);
    }
  }
  __syncthreads();
  const ushort* lw1H = lw1s;
  const ushort* lw1L = lw1s + 8 * 256 * 8;
  f32x4 acc1[4][4];
#pragma unroll
  for (int i = 0; i < 4; ++i)
#pragma unroll
    for (int j = 0; j < 4; ++j) acc1[i][j] = (f32x4){0.f, 0.f, 0.f, 0.f};
#pragma unroll
  for (int ks = 0; ks < 2; ++ks) {
    bf16x8 ah[4], al[4];
#pragma unroll
    for (int fm = 0; fm < 4; ++fm) {
      int idx = ((ks * 4 + l4) * 64 + fm * 16 + l15) * 8;
      ah[fm] = *(const bf16x8*)&featH[idx];
      al[fm] = *(const bf16x8*)&featL[idx];
    }
#pragma unroll
    for (int fn = 0; fn < 4; ++fn) {
      int col = wbase + fn * 16 + l15;
      size_t boff = ((size_t)(ks * 4 + l4) * 256 + col) * 8;
      bf16x8 bh = *(const bf16x8*)(lw1H + boff);
      bf16x8 bl = *(const bf16x8*)(lw1L + boff);
#pragma unroll
      for (int fm = 0; fm < 4; ++fm) {
        acc1[fm][fn] = __builtin_amdgcn_mfma_f32_16x16x32_bf16(al[fm], bh, acc1[fm][fn], 0, 0, 0);
        acc1[fm][fn] = __builtin_amdgcn_mfma_f32_16x16x32_bf16(ah[fm], bl, acc1[fm][fn], 0, 0, 0);
        acc1[fm][fn] = __builtin_amdgcn_mfma_f32_16x16x32_bf16(ah[fm], bh, acc1[fm][fn], 0, 0, 0);
      }
    }
  }
#pragma unroll
  for (int fn = 0; fn < 4; ++fn) {
    int chan = wbase + fn * 16 + l15;
    float bias = lb1[chan];
    int kb = chan >> 3, k7 = chan & 7;
#pragma unroll
    for (int fm = 0; fm < 4; ++fm) {
#pragma unroll
      for (int r = 0; r < 4; ++r) {
        int edge = fm * 16 + l4 * 4 + r;
        float v = fmaxf(acc1[fm][fn][r] + bias, 0.f);
        ushort hi = f2bf(v);
        ushort lo = f2bf(v - bf2f(hi));
        int idx = (kb * 64 + edge) * 8 + k7;
        t1H[idx] = hi;
        t1L[idx] = lo;
      }
    }
  }
  __syncthreads();
  const ushort* lw2H = lw2s;
  const ushort* lw2L = lw2s + 32 * 256 * 8;
  f32x4 acc2[4][4];
#pragma unroll
  for (int i = 0; i < 4; ++i)
#pragma unroll
    for (int j = 0; j < 4; ++j) acc2[i][j] = (f32x4){0.f, 0.f, 0.f, 0.f};
#pragma unroll
  for (int ks = 0; ks < 8; ++ks) {
    bf16x8 ah[4], al[4];
#pragma unroll
    for (int fm = 0; fm < 4; ++fm) {
      int idx = ((ks * 4 + l4) * 64 + fm * 16 + l15) * 8;
      ah[fm] = *(const bf16x8*)&t1H[idx];
      al[fm] = *(const bf16x8*)&t1L[idx];
    }
#pragma unroll
    for (int fn = 0; fn < 4; ++fn) {
      int col = wbase + fn * 16 + l15;
      size_t boff = ((size_t)(ks * 4 + l4) * 256 + col) * 8;
      bf16x8 bh = *(const bf16x8*)(lw2H + boff);
      bf16x8 bl = *(const bf16x8*)(lw2L + boff);
#pragma unroll
      for (int fm = 0; fm < 4; ++fm) {
        acc2[fm][fn] = __builtin_amdgcn_mfma_f32_16x16x32_bf16(al[fm], bh, acc2[fm][fn], 0, 0, 0);
        acc2[fm][fn] = __builtin_amdgcn_mfma_f32_16x16x32_bf16(ah[fm], bl, acc2[fm][fn], 0, 0, 0);
        acc2[fm][fn] = __builtin_amdgcn_mfma_f32_16x16x32_bf16(ah[fm], bh, acc2[fm][fn], 0, 0, 0);
      }
    }
  }
#pragma unroll
  for (int fn = 0; fn < 4; ++fn) {
    int col = wbase + fn * 16 + l15;
    float m0 = -INFINITY, m1 = -INFINITY;
#pragma unroll
    for (int r = 0; r < 4; ++r) {
      m0 = fmaxf(m0, fmaxf(acc2[0][fn][r], acc2[1][fn][r]));
      m1 = fmaxf(m1, fmaxf(acc2[2][fn][r], acc2[3][fn][r]));
    }
    m0 = fmaxf(m0, __shfl_xor(m0, 16));
    m0 = fmaxf(m0, __shfl_xor(m0, 32));
    m1 = fmaxf(m1, __shfl_xor(m1, 16));
    m1 = fmaxf(m1, __shfl_xor(m1, 32));
    if (l4 == 0) {
      float bias = lb2[col];
      int c0 = blockIdx.x * 2;
      split_store(m0 + bias, hH, hL, (size_t)c0 * 256 + col);
      split_store(m1 + bias, hH, hL, (size_t)(c0 + 1) * 256 + col);
    }
  }
}

// ---------------------------------------------------------------------------
// Split-plane MFMA GEMM (round-7 structure; measured-best launch_bounds(256,2)).
// ---------------------------------------------------------------------------
template <int EPI, int OUTS, int BM>
__global__ __launch_bounds__(256, 2)
void gemm_s(const ushort* __restrict__ AH, const ushort* __restrict__ AL,
            const ushort* __restrict__ Wh, const ushort* __restrict__ Wl,
            const float* __restrict__ bias, const float* __restrict__ gamma,
            const float* __restrict__ resid, float* __restrict__ C,
            ushort* __restrict__ CH, ushort* __restrict__ CL,
            int M, int N, int K) {
  constexpr int FN = (BM == 128) ? 4 : 2;
  __shared__ __align__(16) ushort Ah[BM * 32], Al[BM * 32];
  __shared__ __align__(16) ushort Bh[4096], Bl[4096];
  int tid = threadIdx.x;
  int bn = blockIdx.x << 7, bm = blockIdx.y * BM;
  int wid = tid >> 6, lane = tid & 63;
  int wr = (BM == 128) ? (wid >> 1) : 0;
  int wc = (BM == 128) ? (wid & 1) : wid;
  int l15 = lane & 15, l4 = lane >> 4;

  int arow = (BM == 128) ? (tid >> 1) : (tid & 63);
  int akb0 = (BM == 128) ? ((tid & 1) << 1) : (tid >> 6);
  const ushort* ApH = AH + (size_t)(bm + arow) * K + akb0 * 8;
  const ushort* ApL = AL + (size_t)(bm + arow) * K + akb0 * 8;
  int wkb = tid >> 7, wn = tid & 127;

  f32x4 acc[4][FN];
#pragma unroll
  for (int i = 0; i < 4; ++i)
#pragma unroll
    for (int j = 0; j < FN; ++j) acc[i][j] = (f32x4){0.f, 0.f, 0.f, 0.f};

  uint4 aH0 = *(const uint4*)(ApH);
  uint4 aL0 = *(const uint4*)(ApL);
  uint4 aH1, aL1;
  if (BM == 128) {
    aH1 = *(const uint4*)(ApH + 8);
    aL1 = *(const uint4*)(ApL + 8);
  }
  size_t wo1 = ((size_t)wkb * N + bn + wn) * 8;
  size_t wo2 = ((size_t)(wkb + 2) * N + bn + wn) * 8;
  uint4 w0 = *(const uint4*)(Wh + wo1);
  uint4 w1 = *(const uint4*)(Wh + wo2);
  uint4 w2 = *(const uint4*)(Wl + wo1);
  uint4 w3 = *(const uint4*)(Wl + wo2);

  int nkt = K >> 5;
  for (int kt = 0; kt < nkt; ++kt) {
    if (BM == 128) {
      *(uint4*)&Ah[(akb0 * 128 + arow) * 8] = aH0;
      *(uint4*)&Ah[((akb0 + 1) * 128 + arow) * 8] = aH1;
      *(uint4*)&Al[(akb0 * 128 + arow) * 8] = aL0;
      *(uint4*)&Al[((akb0 + 1) * 128 + arow) * 8] = aL1;
    } else {
      *(uint4*)&Ah[(akb0 * 64 + arow) * 8] = aH0;
      *(uint4*)&Al[(akb0 * 64 + arow) * 8] = aL0;
    }
    *(uint4*)&Bh[tid * 8] = w0;
    *(uint4*)&Bh[(tid + 256) * 8] = w1;
    *(uint4*)&Bl[tid * 8] = w2;
    *(uint4*)&Bl[(tid + 256) * 8] = w3;
    __syncthreads();
    if (kt + 1 < nkt) {
      aH0 = *(const uint4*)(ApH + (kt + 1) * 32);
      aL0 = *(const uint4*)(ApL + (kt + 1) * 32);
      if (BM == 128) {
        aH1 = *(const uint4*)(ApH + (kt + 1) * 32 + 8);
        aL1 = *(const uint4*)(ApL + (kt + 1) * 32 + 8);
      }
      size_t b1 = ((size_t)((kt + 1) * 4 + wkb) * N + bn + wn) * 8;
      size_t b2 = ((size_t)((kt + 1) * 4 + wkb + 2) * N + bn + wn) * 8;
      w0 = *(const uint4*)(Wh + b1);
      w1 = *(const uint4*)(Wh + b2);
      w2 = *(const uint4*)(Wl + b1);
      w3 = *(const uint4*)(Wl + b2);
    }
    bf16x8 ahf[4], alf[4];
#pragma unroll
    for (int fm = 0; fm < 4; ++fm) {
      int ci = l4 * BM + wr * 64 + fm * 16 + l15;
      ahf[fm] = *(bf16x8*)&Ah[ci * 8];
      alf[fm] = *(bf16x8*)&Al[ci * 8];
    }
#pragma unroll
    for (int fn = 0; fn < FN; ++fn) {
      int ci = l4 * 128 + wc * (FN * 16) + fn * 16 + l15;
      bf16x8 bh = *(bf16x8*)&Bh[ci * 8];
      bf16x8 bl = *(bf16x8*)&Bl[ci * 8];
#pragma unroll
      for (int fm = 0; fm < 4; ++fm) {
        acc[fm][fn] = __builtin_amdgcn_mfma_f32_16x16x32_bf16(alf[fm], bh, acc[fm][fn], 0, 0, 0);
        acc[fm][fn] = __builtin_amdgcn_mfma_f32_16x16x32_bf16(ahf[fm], bl, acc[fm][fn], 0, 0, 0);
        acc[fm][fn] = __builtin_amdgcn_mfma_f32_16x16x32_bf16(ahf[fm], bh, acc[fm][fn], 0, 0, 0);
      }
    }
    __syncthreads();
  }

#pragma unroll
  for (int fn = 0; fn < FN; ++fn) {
    int col = bn + wc * (FN * 16) + fn * 16 + l15;
    float bv = bias[col];
    float gv = (EPI == 3) ? gamma[col] : 0.f;
#pragma unroll
    for (int fm = 0; fm < 4; ++fm) {
      int row0 = bm + wr * 64 + fm * 16 + l4 * 4;
#pragma unroll
      for (int r = 0; r < 4; ++r) {
        float v = acc[fm][fn][r] + bv;
        if (EPI == 1) v = fmaxf(v, 0.f);
        else if (EPI == 2) v = gelu_f(v);
        else if (EPI == 3) v = resid[(size_t)(row0 + r) * N + col] + gv * v;
        size_t off = (size_t)(row0 + r) * N + col;
        if (OUTS == 0) C[off] = v;
        else split_store(v, CH, CL, off);
      }
    }
  }
}

// ---------------------------------------------------------------------------
// Positional-embedding add.
// ---------------------------------------------------------------------------
__global__ __launch_bounds__(256)
void pe_add(const float* __restrict__ centers, const float* __restrict__ ew,
            const float* __restrict__ eb, float* x) {
  __shared__ float fc[51];
  int c = blockIdx.x, tid = threadIdx.x;
  if (tid < 24) {
    int a = tid >> 3, f = tid & 7;
    float coord = centers[c * 3 + a];
    float p = coord * (float)(M_PI * (double)(1 << f));
    fc[3 + tid] = sinf(p);
    fc[27 + tid] = cosf(p);
  } else if (tid < 27) {
    fc[tid - 24] = centers[c * 3 + (tid - 24)];
  }
  __syncthreads();
  for (int j = tid; j < NDIM; j += 256) {
    float acc = eb[j];
#pragma unroll
    for (int d = 0; d < 51; ++d) acc = fmaf(fc[d], ew[d * NDIM + j], acc);
    x[(size_t)c * NDIM + j] += acc;
  }
}

// ---------------------------------------------------------------------------
// LayerNorm fp32-out (final) and split-out (in-loop).
// ---------------------------------------------------------------------------
__global__ __launch_bounds__(256)
void ln_f32(const float* __restrict__ x, const float* __restrict__ g,
            const float* __restrict__ b, float* __restrict__ y) {
  int row = (blockIdx.x << 2) + (threadIdx.x >> 6);
  int lane = threadIdx.x & 63;
  const float* xr = x + (size_t)row * NDIM;
  float v[6];
#pragma unroll
  for (int i = 0; i < 6; ++i) v[i] = xr[lane + (i << 6)];
  float s = 0.f;
#pragma unroll
  for (int i = 0; i < 6; ++i) s += v[i];
#pragma unroll
  for (int off = 32; off; off >>= 1) s += __shfl_xor(s, off);
  float m = s / 384.f;
  float var = 0.f;
#pragma unroll
  for (int i = 0; i < 6; ++i) { float dd = v[i] - m; var += dd * dd; }
#pragma unroll
  for (int off = 32; off; off >>= 1) var += __shfl_xor(var, off);
  var = var / 384.f;
  float rs = 1.f / sqrtf(var + 1e-6f);
#pragma unroll
  for (int i = 0; i < 6; ++i) {
    int cc = lane + (i << 6);
    y[(size_t)row * NDIM + cc] = (v[i] - m) * rs * g[cc] + b[cc];
  }
}

__global__ __launch_bounds__(256)
void ln_split(const float* __restrict__ x, const float* __restrict__ g,
              const float* __restrict__ b, ushort* __restrict__ yH,
              ushort* __restrict__ yL) {
  int row = (blockIdx.x << 2) + (threadIdx.x >> 6);
  int lane = threadIdx.x & 63;
  const float* xr = x + (size_t)row * NDIM;
  float v[6];
#pragma unroll
  for (int i = 0; i < 6; ++i) v[i] = xr[lane + (i << 6)];
  float s = 0.f;
#pragma unroll
  for (int i = 0; i < 6; ++i) s += v[i];
#pragma unroll
  for (int off = 32; off; off >>= 1) s += __shfl_xor(s, off);
  float m = s / 384.f;
  float var = 0.f;
#pragma unroll
  for (int i = 0; i < 6; ++i) { float dd = v[i] - m; var += dd * dd; }
#pragma unroll
  for (int off = 32; off; off >>= 1) var += __shfl_xor(var, off);
  var = var / 384.f;
  float rs = 1.f / sqrtf(var + 1e-6f);
#pragma unroll
  for (int i = 0; i < 6; ++i) {
    int cc = lane + (i << 6);
    float yv = (v[i] - m) * rs * g[cc] + b[cc];
    split_store(yv, yH, yL, (size_t)row * NDIM + cc);
  }
}

// ---------------------------------------------------------------------------
// MFMA flash attention on split planes.
// ---------------------------------------------------------------------------
__global__ __launch_bounds__(256, 2)
void attn_mfma(const ushort* __restrict__ FH, const ushort* __restrict__ FL,
               ushort* __restrict__ oH, ushort* __restrict__ oL) {
  __shared__ __align__(16) ushort kTH[4096], kTL[4096];
  __shared__ __align__(16) ushort vSH[4096], vSL[4096];
  __shared__ __align__(16) ushort pSH[8192], pSL[8192];
  int bi = blockIdx.x;
  int qt = bi & 3;
  int hh = (bi >> 2) % 6;
  int b = bi / 24;
  int tid = threadIdx.x;
  int w = tid >> 6, lane = tid & 63;
  int l15 = lane & 15, l4 = lane >> 4;
  const ushort* baseH = FH + (size_t)(b * NCTR) * 1152;
  const ushort* baseL = FL + (size_t)(b * NCTR) * 1152;
  int qbase = qt * 128 + w * 32;

  bf16x8 qh[2][2], ql[2][2];
#pragma unroll
  for (int qr = 0; qr < 2; ++qr) {
#pragma unroll
    for (int ds = 0; ds < 2; ++ds) {
      size_t off = (size_t)(qbase + qr * 16 + l15) * 1152 + hh * 64 + ds * 32 + l4 * 8;
      qh[qr][ds] = *(const bf16x8*)(baseH + off);
      ql[qr][ds] = *(const bf16x8*)(baseL + off);
    }
  }

  f32x4 oacc[2][4];
#pragma unroll
  for (int i = 0; i < 2; ++i)
#pragma unroll
    for (int j = 0; j < 4; ++j) oacc[i][j] = (f32x4){0.f, 0.f, 0.f, 0.f};
  float m_[2][4], l_[2][4];
#pragma unroll
  for (int i = 0; i < 2; ++i)
#pragma unroll
    for (int r = 0; r < 4; ++r) { m_[i][r] = -INFINITY; l_[i][r] = 0.f; }

  ushort* pHw = pSH + w * 2048;
  ushort* pLw = pSL + w * 2048;

  for (int ch = 0; ch < 8; ++ch) {
    {
      int key = tid & 63, dgh = tid >> 6;
      size_t krow = (size_t)(ch * 64 + key) * 1152 + 384 + hh * 64;
#pragma unroll
      for (int i = 0; i < 2; ++i) {
        int dg = dgh * 2 + i;
        *(uint4*)&kTH[(dg * 64 + key) * 8] = *(const uint4*)(baseH + krow + dg * 8);
        *(uint4*)&kTL[(dg * 64 + key) * 8] = *(const uint4*)(baseL + krow + dg * 8);
      }
      int d = tid & 63, kb2 = tid >> 6;
#pragma unroll
      for (int i = 0; i < 2; ++i) {
        int kb = kb2 + i * 4;
        ushort hv[8], lv[8];
#pragma unroll
        for (int j = 0; j < 8; ++j) {
          size_t off = (size_t)(ch * 64 + kb * 8 + j) * 1152 + 768 + hh * 64 + d;
          hv[j] = baseH[off];
          lv[j] = baseL[off];
        }
        uint4 H, L;
        H.x = (uint)hv[0] | ((uint)hv[1] << 16); H.y = (uint)hv[2] | ((uint)hv[3] << 16);
        H.z = (uint)hv[4] | ((uint)hv[5] << 16); H.w = (uint)hv[6] | ((uint)hv[7] << 16);
        L.x = (uint)lv[0] | ((uint)lv[1] << 16); L.y = (uint)lv[2] | ((uint)lv[3] << 16);
        L.z = (uint)lv[4] | ((uint)lv[5] << 16); L.w = (uint)lv[6] | ((uint)lv[7] << 16);
        *(uint4*)&vSH[(kb * 64 + d) * 8] = H;
        *(uint4*)&vSL[(kb * 64 + d) * 8] = L;
      }
    }
    __syncthreads();

    f32x4 sacc[2][4];
#pragma unroll
    for (int i = 0; i < 2; ++i)
#pragma unroll
      for (int j = 0; j < 4; ++j) sacc[i][j] = (f32x4){0.f, 0.f, 0.f, 0.f};
#pragma unroll
    for (int ds = 0; ds < 2; ++ds) {
#pragma unroll
      for (int kc = 0; kc < 4; ++kc) {
        int idx = ((ds * 4 + l4) * 64 + kc * 16 + l15) * 8;
        bf16x8 bh = *(const bf16x8*)&kTH[idx];
        bf16x8 bl = *(const bf16x8*)&kTL[idx];
#pragma unroll
        for (int qr = 0; qr < 2; ++qr) {
          sacc[qr][kc] = __builtin_amdgcn_mfma_f32_16x16x32_bf16(ql[qr][ds], bh, sacc[qr][kc], 0, 0, 0);
          sacc[qr][kc] = __builtin_amdgcn_mfma_f32_16x16x32_bf16(qh[qr][ds], bl, sacc[qr][kc], 0, 0, 0);
          sacc[qr][kc] = __builtin_amdgcn_mfma_f32_16x16x32_bf16(qh[qr][ds], bh, sacc[qr][kc], 0, 0, 0);
        }
      }
    }

    float t[2][4];
#pragma unroll
    for (int qr = 0; qr < 2; ++qr)
#pragma unroll
      for (int r = 0; r < 4; ++r) {
        float a0 = sacc[qr][0][r] * 0.125f; sacc[qr][0][r] = a0;
        float a1 = sacc[qr][1][r] * 0.125f; sacc[qr][1][r] = a1;
        float a2 = sacc[qr][2][r] * 0.125f; sacc[qr][2][r] = a2;
        float a3 = sacc[qr][3][r] * 0.125f; sacc[qr][3][r] = a3;
        t[qr][r] = fmaxf(fmaxf(a0, a1), fmaxf(a2, a3));
      }
#pragma unroll
    for (int off = 1; off < 16; off <<= 1)
#pragma unroll
      for (int qr = 0; qr < 2; ++qr)
#pragma unroll
        for (int r = 0; r < 4; ++r)
          t[qr][r] = fmaxf(t[qr][r], __shfl_xor(t[qr][r], off));
    float f_[2][4];
#pragma unroll
    for (int qr = 0; qr < 2; ++qr)
#pragma unroll
      for (int r = 0; r < 4; ++r) {
        float mn = fmaxf(m_[qr][r], t[qr][r]);
        f_[qr][r] = expf(m_[qr][r] - mn);
        m_[qr][r] = mn;
      }
#pragma unroll
    for (int qr = 0; qr < 2; ++qr)
#pragma unroll
      for (int dc = 0; dc < 4; ++dc)
#pragma unroll
        for (int r = 0; r < 4; ++r) oacc[qr][dc][r] *= f_[qr][r];
    float sm[2][4];
#pragma unroll
    for (int qr = 0; qr < 2; ++qr)
#pragma unroll
      for (int r = 0; r < 4; ++r) {
        float p0 = expf(sacc[qr][0][r] - m_[qr][r]); sacc[qr][0][r] = p0;
        float p1 = expf(sacc[qr][1][r] - m_[qr][r]); sacc[qr][1][r] = p1;
        float p2 = expf(sacc[qr][2][r] - m_[qr][r]); sacc[qr][2][r] = p2;
        float p3 = expf(sacc[qr][3][r] - m_[qr][r]); sacc[qr][3][r] = p3;
        sm[qr][r] = ((p0 + p1) + (p2 + p3));
      }
#pragma unroll
    for (int off = 1; off < 16; off <<= 1)
#pragma unroll
      for (int qr = 0; qr < 2; ++qr)
#pragma unroll
        for (int r = 0; r < 4; ++r)
          sm[qr][r] += __shfl_xor(sm[qr][r], off);
#pragma unroll
    for (int qr = 0; qr < 2; ++qr)
#pragma unroll
      for (int r = 0; r < 4; ++r) l_[qr][r] = l_[qr][r] * f_[qr][r] + sm[qr][r];

#pragma unroll
    for (int qr = 0; qr < 2; ++qr)
#pragma unroll
      for (int kc = 0; kc < 4; ++kc)
#pragma unroll
        for (int r = 0; r < 4; ++r) {
          float pv = sacc[qr][kc][r];
          ushort hi = f2bf(pv);
          ushort lo = f2bf(pv - bf2f(hi));
          int k = kc * 16 + l15;
          int qrow = qr * 16 + l4 * 4 + r;
          int idx = ((k >> 3) * 32 + qrow) * 8 + (k & 7);
          pHw[idx] = hi;
          pLw[idx] = lo;
        }

#pragma unroll
    for (int ks = 0; ks < 2; ++ks) {
      bf16x8 pah[2], pal[2];
#pragma unroll
      for (int qr = 0; qr < 2; ++qr) {
        int idx = ((ks * 4 + l4) * 32 + qr * 16 + l15) * 8;
        pah[qr] = *(const bf16x8*)&pHw[idx];
        pal[qr] = *(const bf16x8*)&pLw[idx];
      }
#pragma unroll
      for (int dc = 0; dc < 4; ++dc) {
        int idx = ((ks * 4 + l4) * 64 + dc * 16 + l15) * 8;
        bf16x8 vh = *(const bf16x8*)&vSH[idx];
        bf16x8 vl = *(const bf16x8*)&vSL[idx];
#pragma unroll
        for (int qr = 0; qr < 2; ++qr) {
          oacc[qr][dc] = __builtin_amdgcn_mfma_f32_16x16x32_bf16(pal[qr], vh, oacc[qr][dc], 0, 0, 0);
          oacc[qr][dc] = __builtin_amdgcn_mfma_f32_16x16x32_bf16(pah[qr], vl, oacc[qr][dc], 0, 0, 0);
          oacc[qr][dc] = __builtin_amdgcn_mfma_f32_16x16x32_bf16(pah[qr], vh, oacc[qr][dc], 0, 0, 0);
        }
      }
    }
    __syncthreads();
  }

  float il[2][4];
#pragma unroll
  for (int qr = 0; qr < 2; ++qr)
#pragma unroll
    for (int r = 0; r < 4; ++r) il[qr][r] = 1.f / l_[qr][r];
#pragma unroll
  for (int qr = 0; qr < 2; ++qr)
#pragma unroll
    for (int dc = 0; dc < 4; ++dc)
#pragma unroll
      for (int r = 0; r < 4; ++r) {
        int row = b * NCTR + qbase + qr * 16 + l4 * 4 + r;
        int col = hh * 64 + dc * 16 + l15;
        split_store(oacc[qr][dc][r] * il[qr][r], oH, oL, (size_t)row * NDIM + col);
      }
}

// ---------------------------------------------------------------------------
extern "C" void kernel_launch(void* const* d_in, const int* in_sizes, int n_in,
                              void* d_out, int out_size, void* d_ws, size_t ws_size,
                              hipStream_t stream) {
  const float* pc      = (const float*)d_in[0];
  const float* embed_w = (const float*)d_in[1];
  const float* embed_b = (const float*)d_in[2];
  const float* lw1     = (const float*)d_in[3];
  const float* lb1     = (const float*)d_in[4];
  const float* lw2     = (const float*)d_in[5];
  const float* lb2     = (const float*)d_in[6];
  const float* gw1     = (const float*)d_in[7];
  const float* gb1     = (const float*)d_in[8];
  const float* gw2     = (const float*)d_in[9];
  const float* gb2     = (const float*)d_in[10];
  const float* ln1_g   = (const float*)d_in[11];
  const float* ln1_b   = (const float*)d_in[12];
  const float* qkv_w   = (const float*)d_in[13];
  const float* qkv_b   = (const float*)d_in[14];
  const float* proj_w  = (const float*)d_in[15];
  const float* proj_b  = (const float*)d_in[16];
  const float* gamma1  = (const float*)d_in[17];
  const float* ln2_g   = (const float*)d_in[18];
  const float* ln2_b   = (const float*)d_in[19];
  const float* fc1_w   = (const float*)d_in[20];
  const float* fc1_b   = (const float*)d_in[21];
  const float* fc2_w   = (const float*)d_in[22];
  const float* fc2_b   = (const float*)d_in[23];
  const float* gamma2  = (const float*)d_in[24];
  const float* lnf_g   = (const float*)d_in[25];
  const float* lnf_b   = (const float*)d_in[26];

  float* out = (float*)d_out;
  float* centers = out + (size_t)NB * NCTR * NDIM;

  char* ws = (char*)d_ws;
  int*    nn  = (int*)(ws + 0);
  float*  x   = (float*)(ws + 1048576);
  ushort* xnH = (ushort*)(ws + 13631488);
  ushort* xnL = (ushort*)(ws + 19922944);
  ushort* FH  = (ushort*)(ws + 26214400);
  ushort* FL  = (ushort*)(ws + 51380224);
  ushort* hH  = (ushort*)(ws + 76546048);
  ushort* hL  = (ushort*)(ws + 80740352);
  ushort* wsplit = (ushort*)(ws + 84934656);

  // --- weight pre-split descriptor (runs merged with FPS) ---
  WAll wa;
  const float* srcs[8] = {qkv_w, proj_w, fc1_w, fc2_w, gw1, gw2, lw1, lw2};
  int kpads[8] = {2304, 2304, 2304, 9216, 256, 256, 64, 256};
  int ns[8]    = {1152, 384, 1536, 384, 256, 384, 256, 256};
  int ksrcs[8] = {2304, 2304, 2304, 9216, 256, 256, 51, 256};
  ushort* dsts[8];
  size_t wofs = 0;
  int cum = 0;
  for (int f = 0; f < 8; ++f) {
    dsts[f] = wsplit + wofs;
    wofs += (size_t)2 * kpads[f] * ns[f];
    wa.src[f] = srcs[f];
    wa.dst[f] = dsts[f];
    wa.K8[f] = kpads[f] >> 3;
    wa.N[f] = ns[f];
    wa.Ksrc[f] = ksrcs[f];
    wa.blk0[f] = cum;
    cum += ((kpads[f] >> 3) * ns[f] + 255) / 256;
  }
  wa.blk0[8] = cum;
  ushort* qkvS = dsts[0];
  ushort* projS = dsts[1];
  ushort* fc1S = dsts[2];
  ushort* fc2S = dsts[3];
  ushort* g1S = dsts[4];
  ushort* g2S = dsts[5];
  ushort* lw1s = dsts[6];
  ushort* lw2s = dsts[7];

  // --- FPS (blocks 0..15) + weight split (rest) in one launch ---
  fps_wconv<<<16 + cum, 256, 0, stream>>>(pc, centers, wa);
  knn_kernel<<<2048, 256, 0, stream>>>(pc, centers, nn);
  edge_mfma<<<4096, 256, 0, stream>>>(pc, centers, nn, lw1s, lb1, lw2s, lb2, hH, hL);

  gemm_s<1, 1, 64><<<dim3(2, 128), 256, 0, stream>>>(
      hH, hL, g1S, g1S + 65536, gb1, nullptr, nullptr, nullptr, xnH, xnL,
      8192, 256, 256);
  gemm_s<0, 0, 64><<<dim3(3, 128), 256, 0, stream>>>(
      xnH, xnL, g2S, g2S + 98304, gb2, nullptr, nullptr, x, nullptr, nullptr,
      8192, 384, 256);
  pe_add<<<8192, 256, 0, stream>>>(centers, embed_w, embed_b, x);

  for (int l = 0; l < 6; ++l) {
    ln_split<<<2048, 256, 0, stream>>>(x, ln1_g + l * 384, ln1_b + l * 384, xnH, xnL);
    gemm_s<0, 1, 128><<<dim3(9, 64), 256, 0, stream>>>(
        xnH, xnL, qkvS + (size_t)l * 442368, qkvS + 2654208 + (size_t)l * 442368,
        qkv_b + l * 1152, nullptr, nullptr, nullptr, FH, FL, 8192, 1152, 384);
    attn_mfma<<<384, 256, 0, stream>>>(FH, FL, xnH, xnL);
    gemm_s<3, 0, 64><<<dim3(3, 128), 256, 0, stream>>>(
        xnH, xnL, projS + (size_t)l * 147456, projS + 884736 + (size_t)l * 147456,
        proj_b + l * 384, gamma1 + l * 384, x, x, nullptr, nullptr, 8192, 384, 384);
    ln_split<<<2048, 256, 0, stream>>>(x, ln2_g + l * 384, ln2_b + l * 384, xnH, xnL);
    gemm_s<2, 1, 128><<<dim3(12, 64), 256, 0, stream>>>(
        xnH, xnL, fc1S + (size_t)l * 589824, fc1S + 3538944 + (size_t)l * 589824,
        fc1_b + l * 1536, nullptr, nullptr, nullptr, FH, FL, 8192, 1536, 384);
    gemm_s<3, 0, 64><<<dim3(3, 128), 256, 0, stream>>>(
        FH, FL, fc2S + (size_t)l * 589824, fc2S + 3538944 + (size_t)l * 589824,
        fc2_b + l * 384, gamma2 + l * 384, x, x, nullptr, nullptr, 8192, 384, 1536);
  }
  ln_f32<<<2048, 256, 0, stream>>>(x, lnf_g, lnf_b, out);
}